// Round 2
// baseline (380.067 us; speedup 1.0000x reference)
//
#include <hip/hip_runtime.h>
#include <hip/hip_bf16.h>
#include <cstdint>
#include <cstddef>

#define KDIM 4096   // IN_F
#define NDIM 4096   // OUT_F

typedef __attribute__((ext_vector_type(8))) short short8;
typedef __attribute__((ext_vector_type(8))) __bf16 bf16x8;
typedef __attribute__((ext_vector_type(4))) float f32x4;

// f32 -> bf16, round-to-nearest-even
__device__ __forceinline__ unsigned short bf16_rne(float f) {
    unsigned int u = __builtin_bit_cast(unsigned int, f);
    u += 0x7fffu + ((u >> 16) & 1u);
    return (unsigned short)(u >> 16);
}

__device__ __forceinline__ void gload_lds16(const unsigned short* g, unsigned short* l) {
    __builtin_amdgcn_global_load_lds(
        (const __attribute__((address_space(1))) unsigned int*)g,
        (__attribute__((address_space(3))) unsigned int*)l,
        16, 0, 0);
}

// ---------------- preprocess: x fp32 -> bf16 ----------------
__global__ void cvt_x_kernel(const float* __restrict__ x, unsigned short* __restrict__ xb) {
    long i = (long)blockIdx.x * blockDim.x + threadIdx.x;   // one thread = 8 elems
    float4 a = ((const float4*)x)[2 * i];
    float4 b = ((const float4*)x)[2 * i + 1];
    union { unsigned short u[8]; short8 v; } r;
    r.u[0] = bf16_rne(a.x); r.u[1] = bf16_rne(a.y);
    r.u[2] = bf16_rne(a.z); r.u[3] = bf16_rne(a.w);
    r.u[4] = bf16_rne(b.x); r.u[5] = bf16_rne(b.y);
    r.u[6] = bf16_rne(b.z); r.u[7] = bf16_rne(b.w);
    ((short8*)xb)[i] = r.v;
}

// ---------------- preprocess: dequant 2-bit W -> bf16 [N][K] ----------------
__global__ void dequant_w_kernel(const int* __restrict__ wp,
                                 const float* __restrict__ scales,
                                 const float* __restrict__ zeros,
                                 unsigned short* __restrict__ wb) {
    long i = (long)blockIdx.x * blockDim.x + threadIdx.x;   // one thread = 2 packed ints = 8 weights
    int2 p = ((const int2*)wp)[i];
    long base = i * 8;                    // flat weight index (o*4096 + k)
    int o = (int)(base >> 12);
    int g = (int)((base & 4095) >> 7);    // all 8 weights in same group (8 | 128)
    float s = scales[o * 32 + g];
    float z = zeros[o * 32 + g];
    union { unsigned short u[8]; short8 v; } r;
#pragma unroll
    for (int j = 0; j < 4; ++j) {
        r.u[j]     = bf16_rne((float)((p.x >> (2 * j)) & 3) * s + z);
        r.u[4 + j] = bf16_rne((float)((p.y >> (2 * j)) & 3) * s + z);
    }
    ((short8*)wb)[i] = r.v;
}

// ---------------- GEMM: C[M][N] = A[M][K](bf16) * B[N][K](bf16)^T + bias ----------------
// m97 structure: 128x128 tile, BK=32, 256 threads (4 waves, 2x2), 4x4 16x16 frags/wave,
// global_load_lds width-16 staging, 2 barriers per K-step.
// Race fix: explicit sched_barrier-pinned s_waitcnt vmcnt(0) BEFORE the barrier —
// do not rely on __syncthreads() codegen to drain the LDS-DMA (vmcnt) queue.
__global__ __launch_bounds__(256) void gemm_bt(const unsigned short* __restrict__ A,
                                               const unsigned short* __restrict__ B,
                                               const float* __restrict__ bias,
                                               float* __restrict__ C) {
    __shared__ __align__(16) unsigned short As[128 * 32];   // 8 KB
    __shared__ __align__(16) unsigned short Bs[128 * 32];   // 8 KB

    const int t = threadIdx.x;
    const int w = t >> 6;          // wave 0..3
    const int l = t & 63;
    const int row0 = blockIdx.x * 128;
    const int col0 = blockIdx.y * 128;
    const int wr = w >> 1, wc = w & 1;   // wave computes 64x64 at (wr,wc)

    f32x4 acc[4][4] = {};

    // staging: thread t covers tile row t/4 (+64 for 2nd inst), k-bytes (t%4)*16
    const int rA = t >> 2;               // 0..63
    const int ks = (t & 3) * 8;          // bf16 elems
    const unsigned short* a0 = A + (size_t)(row0 + rA) * KDIM + ks;
    const unsigned short* a1 = a0 + (size_t)64 * KDIM;
    const unsigned short* b0 = B + (size_t)(col0 + rA) * KDIM + ks;
    const unsigned short* b1 = b0 + (size_t)64 * KDIM;
    unsigned short* lA0 = As + w * 512;          // wave-uniform LDS bases (lane scatter = +l*16B)
    unsigned short* lA1 = As + 2048 + w * 512;
    unsigned short* lB0 = Bs + w * 512;
    unsigned short* lB1 = Bs + 2048 + w * 512;

    const int lr = l & 15;
    const int lk = (l >> 4) * 8;

    for (int k0 = 0; k0 < KDIM; k0 += 32) {
        gload_lds16(a0 + k0, lA0);
        gload_lds16(a1 + k0, lA1);
        gload_lds16(b0 + k0, lB0);
        gload_lds16(b1 + k0, lB1);
        // Explicit drain of the LDS-DMA queue, pinned so the compiler can
        // neither sink the gloads below it nor hoist anything above it.
        __builtin_amdgcn_sched_barrier(0);
        asm volatile("s_waitcnt vmcnt(0)" ::: "memory");
        __builtin_amdgcn_sched_barrier(0);
        __syncthreads();   // all waves' LDS tiles now visible

        short8 af[4], bfr[4];
#pragma unroll
        for (int mi = 0; mi < 4; ++mi)
            af[mi] = *(const short8*)(As + (wr * 64 + mi * 16 + lr) * 32 + lk);
#pragma unroll
        for (int ni = 0; ni < 4; ++ni)
            bfr[ni] = *(const short8*)(Bs + (wc * 64 + ni * 16 + lr) * 32 + lk);

#pragma unroll
        for (int mi = 0; mi < 4; ++mi)
#pragma unroll
            for (int ni = 0; ni < 4; ++ni)
                acc[mi][ni] = __builtin_amdgcn_mfma_f32_16x16x32_bf16(
                    __builtin_bit_cast(bf16x8, af[mi]),
                    __builtin_bit_cast(bf16x8, bfr[ni]),
                    acc[mi][ni], 0, 0, 0);

        __syncthreads();   // protect LDS before next stage (reads complete before writes)
    }

    // epilogue: C/D frag layout col=lane&15, row=(lane>>4)*4+r
#pragma unroll
    for (int mi = 0; mi < 4; ++mi) {
#pragma unroll
        for (int ni = 0; ni < 4; ++ni) {
            int col = col0 + wc * 64 + ni * 16 + (l & 15);
            float bz = bias[col];
#pragma unroll
            for (int r = 0; r < 4; ++r) {
                int row = row0 + wr * 64 + mi * 16 + (l >> 4) * 4 + r;
                C[(size_t)row * NDIM + col] = acc[mi][ni][r] + bz;
            }
        }
    }
}

// ---------------- emergency fallback (ws too small): exact fp32, fused dequant ----------------
__global__ void fallback_kernel(const float* __restrict__ x, const int* __restrict__ wp,
                                const float* __restrict__ scales, const float* __restrict__ zeros,
                                const float* __restrict__ bias, float* __restrict__ out) {
    int o = blockIdx.x * 256 + threadIdx.x;
    int m = blockIdx.y;
    __shared__ float xs[KDIM];
    for (int i = threadIdx.x; i < KDIM; i += 256) xs[i] = x[(size_t)m * KDIM + i];
    __syncthreads();
    float acc = 0.f;
    for (int g = 0; g < 32; ++g) {
        float s = scales[o * 32 + g], z = zeros[o * 32 + g];
        float aq = 0.f, ax = 0.f;
        for (int j = 0; j < 32; ++j) {
            int p = wp[o * 1024 + g * 32 + j];
            int kb = g * 128 + j * 4;
#pragma unroll
            for (int q = 0; q < 4; ++q) {
                float xv = xs[kb + q];
                aq += xv * (float)((p >> (2 * q)) & 3);
                ax += xv;
            }
        }
        acc += s * aq + z * ax;
    }
    out[(size_t)m * NDIM + o] = acc + bias[o];
}

extern "C" void kernel_launch(void* const* d_in, const int* in_sizes, int n_in,
                              void* d_out, int out_size, void* d_ws, size_t ws_size,
                              hipStream_t stream) {
    const float* x      = (const float*)d_in[0];
    const int*   wp     = (const int*)d_in[1];
    const float* scales = (const float*)d_in[2];
    const float* zeros  = (const float*)d_in[3];
    const float* bias   = (const float*)d_in[4];
    float* out = (float*)d_out;

    const long M = (long)in_sizes[0] / KDIM;            // 8192
    const long PACKED = (long)in_sizes[1];              // 4194304
    const size_t need = (size_t)M * KDIM * 2 + (size_t)NDIM * KDIM * 2;  // 96 MB

    if (ws_size >= need) {
        unsigned short* xb = (unsigned short*)d_ws;
        unsigned short* wb = xb + (size_t)M * KDIM;
        cvt_x_kernel<<<(M * KDIM / 8) / 256, 256, 0, stream>>>(x, xb);
        dequant_w_kernel<<<(PACKED / 2) / 256, 256, 0, stream>>>(wp, scales, zeros, wb);
        dim3 grid(M / 128, NDIM / 128);
        gemm_bt<<<grid, 256, 0, stream>>>(xb, wb, bias, out);
    } else {
        dim3 grid(NDIM / 256, M);
        fallback_kernel<<<grid, 256, 0, stream>>>(x, wp, scales, zeros, bias, out);
    }
}

// Round 4
// 297.971 us; speedup vs baseline: 1.2755x; 1.2755x over previous
//
#include <hip/hip_runtime.h>
#include <hip/hip_bf16.h>
#include <cstdint>
#include <cstddef>

#define KDIM 4096   // IN_F
#define NDIM 4096   // OUT_F

typedef __attribute__((ext_vector_type(8))) short short8;
typedef __attribute__((ext_vector_type(8))) __bf16 bf16x8;
typedef __attribute__((ext_vector_type(4))) float f32x4;

// f32 -> bf16, round-to-nearest-even
__device__ __forceinline__ unsigned short bf16_rne(float f) {
    unsigned int u = __builtin_bit_cast(unsigned int, f);
    u += 0x7fffu + ((u >> 16) & 1u);
    return (unsigned short)(u >> 16);
}

__device__ __forceinline__ void gload_lds16(const unsigned short* g, unsigned short* l) {
    __builtin_amdgcn_global_load_lds(
        (const __attribute__((address_space(1))) unsigned int*)g,
        (__attribute__((address_space(3))) unsigned int*)l,
        16, 0, 0);
}

// ---------------- preprocess: x fp32 -> bf16 ----------------
__global__ void cvt_x_kernel(const float* __restrict__ x, unsigned short* __restrict__ xb) {
    long i = (long)blockIdx.x * blockDim.x + threadIdx.x;   // one thread = 8 elems
    float4 a = ((const float4*)x)[2 * i];
    float4 b = ((const float4*)x)[2 * i + 1];
    union { unsigned short u[8]; short8 v; } r;
    r.u[0] = bf16_rne(a.x); r.u[1] = bf16_rne(a.y);
    r.u[2] = bf16_rne(a.z); r.u[3] = bf16_rne(a.w);
    r.u[4] = bf16_rne(b.x); r.u[5] = bf16_rne(b.y);
    r.u[6] = bf16_rne(b.z); r.u[7] = bf16_rne(b.w);
    ((short8*)xb)[i] = r.v;
}

// ---------------- preprocess: dequant 2-bit W -> bf16 [N][K] ----------------
__global__ void dequant_w_kernel(const int* __restrict__ wp,
                                 const float* __restrict__ scales,
                                 const float* __restrict__ zeros,
                                 unsigned short* __restrict__ wb) {
    long i = (long)blockIdx.x * blockDim.x + threadIdx.x;   // one thread = 2 packed ints = 8 weights
    int2 p = ((const int2*)wp)[i];
    long base = i * 8;                    // flat weight index (o*4096 + k)
    int o = (int)(base >> 12);
    int g = (int)((base & 4095) >> 7);    // all 8 weights in same group (8 | 128)
    float s = scales[o * 32 + g];
    float z = zeros[o * 32 + g];
    union { unsigned short u[8]; short8 v; } r;
#pragma unroll
    for (int j = 0; j < 4; ++j) {
        r.u[j]     = bf16_rne((float)((p.x >> (2 * j)) & 3) * s + z);
        r.u[4 + j] = bf16_rne((float)((p.y >> (2 * j)) & 3) * s + z);
    }
    ((short8*)wb)[i] = r.v;
}

// ---------------- 256x256 8-phase GEMM (T1+T2+T3+T4+T5) ----------------
// C[M][N] = A[M][K](bf16) * B[N][K](bf16)^T + bias.
// 512 thr = 8 waves (2Mx4N), per-wave 128x64 out, BK=64, LDS 128 KiB (2 dbuf).
// Swizzle: LDS(r, 8j) holds G(r, 8*(j ^ (r&7))); linear DMA dest + pre-swizzled
// per-lane GLOBAL source + swizzled ds_read (rule #21, both-sides).
//
// REGION LIFETIME LEDGER (buf d = tile t):   [R4 fix: A halves are read at
// P1 AND P3; B halves at P1 AND P2 — staging into buf d must respect this]
//   B regions free after P2-end barrier; A regions free after P3-end barrier.
// STAGE SCHEDULE: P3: B0,B1(t+2)->buf d (B free ✓); P4: vmcnt(4) then
// A0,A1(t+2)->buf d (A free ✓).
// VMCNT: at (t).P4 outstanding = B(t+1)[4]+A(t+1)[4]+B(t+2)[4]=12; vmcnt(4)
// drains all but B(t+2) => tile t+1 fully resident before (t+1).P1.
// Tail: t2 clamped to NT-1 => duplicate idempotent writes (same bytes) keep
// the constant vmcnt(4) valid; post-loop vmcnt(0) so no DMA in flight at end.

#define SYNC_MID \
    __builtin_amdgcn_sched_barrier(0); \
    __builtin_amdgcn_s_barrier(); \
    asm volatile("s_waitcnt lgkmcnt(0)" ::: "memory"); \
    __builtin_amdgcn_sched_barrier(0); \
    __builtin_amdgcn_s_setprio(1);

#define SYNC_END \
    __builtin_amdgcn_s_setprio(0); \
    __builtin_amdgcn_sched_barrier(0); \
    __builtin_amdgcn_s_barrier();

#define QUAD(mh, nh) \
    _Pragma("unroll") \
    for (int s_ = 0; s_ < 2; ++s_) { \
      _Pragma("unroll") \
      for (int mi_ = 0; mi_ < 4; ++mi_) { \
        _Pragma("unroll") \
        for (int ni_ = 0; ni_ < 2; ++ni_) { \
          acc[(mh)*4+mi_][(nh)*2+ni_] = __builtin_amdgcn_mfma_f32_16x16x32_bf16( \
            __builtin_bit_cast(bf16x8, aF[mi_][s_]), \
            __builtin_bit_cast(bf16x8, bF[(nh)*2+ni_][s_]), \
            acc[(mh)*4+mi_][(nh)*2+ni_], 0, 0, 0); \
        } } }

__global__ __launch_bounds__(512, 2) void gemm256(const unsigned short* __restrict__ A,
                                                  const unsigned short* __restrict__ B,
                                                  const float* __restrict__ bias,
                                                  float* __restrict__ C) {
    __shared__ __align__(16) unsigned short sm[65536];   // 128 KiB: buf d: A@d*32768, B@d*32768+16384

    const int tid = threadIdx.x;
    const int w64 = tid >> 6;
    const int lane = tid & 63;

    // T1: bijective XCD swizzle (gridDim.x % 8 == 0)
    const int nwg = gridDim.x;
    const int chunk = nwg >> 3;
    const int s_id = (blockIdx.x & 7) * chunk + (blockIdx.x >> 3);
    const int nm = nwg >> 4;              // M tiles (N tiles fixed at 16)
    const int bm = s_id % nm;
    const int bn = s_id / nm;
    const int row0 = bm * 256;
    const int col0 = bn * 256;

    const int wr = w64 >> 2;              // 0..1 (M half)
    const int wc = w64 & 3;               // 0..3 (N quarter)

    // ---- stage addressing: thread covers row srow(+64j,+128h), 16B at swizzled k
    const int srow = tid >> 3;                                  // 0..63
    const int swzk = 8 * ((tid & 7) ^ ((tid >> 3) & 7));        // elem offset (pre-swizzled src)
    const unsigned short* srcA = A + (size_t)(row0 + srow) * KDIM + swzk;
    const unsigned short* srcB = B + (size_t)(col0 + srow) * KDIM + swzk;

    // ---- frag addressing (swizzled ds_read): elem = R*64 + 8*((4s+lk4)^(R&7)), R&7 == lane&7
    const int lr = lane & 15;
    const int lk4 = lane >> 4;
    const int l7 = lane & 7;
    const int sw0 = 8 * (((0 << 2) + lk4) ^ l7);
    const int sw1 = 8 * (((1 << 2) + lk4) ^ l7);
    const int aBase = (wr * 128 + lr) * 64;
    const int bBase = 16384 + (wc * 64 + lr) * 64;

    f32x4 acc[8][4] = {};
    short8 aF[4][2], bF[4][2];

    auto stageA = [&](int h, int tile, int db) {
        const unsigned short* g = srcA + (size_t)h * 128 * KDIM + (size_t)tile * 64;
        unsigned short* l = &sm[db * 32768 + h * 8192 + w64 * 512];
        gload_lds16(g, l);
        gload_lds16(g + (size_t)64 * KDIM, l + 4096);
    };
    auto stageB = [&](int h, int tile, int db) {
        const unsigned short* g = srcB + (size_t)h * 128 * KDIM + (size_t)tile * 64;
        unsigned short* l = &sm[db * 32768 + 16384 + h * 8192 + w64 * 512];
        gload_lds16(g, l);
        gload_lds16(g + (size_t)64 * KDIM, l + 4096);
    };

    const int NT = KDIM / 64;   // 64 K-tiles

    // ---- prologue: tile0 (8 loads)->buf0, tile1 B then A (8 loads)->buf1
    stageA(0, 0, 0); stageA(1, 0, 0); stageB(0, 0, 0); stageB(1, 0, 0);
    stageB(0, 1, 1); stageB(1, 1, 1); stageA(0, 1, 1); stageA(1, 1, 1);
    __builtin_amdgcn_sched_barrier(0);
    asm volatile("s_waitcnt vmcnt(8)" ::: "memory");   // tile0's 8 loads landed
    __builtin_amdgcn_sched_barrier(0);
    __builtin_amdgcn_s_barrier();

    for (int t = 0; t < NT; ++t) {
        const int d = t & 1;
        const int dOff = d * 32768;
        const int t2 = (t + 2 < NT) ? t + 2 : NT - 1;   // clamped tail: idempotent dup writes

        // ---------- P1: quad (m-half 0, n-half 0) ----------
#pragma unroll
        for (int mi = 0; mi < 4; ++mi) {
            aF[mi][0] = *(const short8*)&sm[dOff + aBase + mi * 1024 + sw0];
            aF[mi][1] = *(const short8*)&sm[dOff + aBase + mi * 1024 + sw1];
        }
#pragma unroll
        for (int ni = 0; ni < 2; ++ni) {
            bF[ni][0] = *(const short8*)&sm[dOff + bBase + ni * 1024 + sw0];
            bF[ni][1] = *(const short8*)&sm[dOff + bBase + ni * 1024 + sw1];
        }
        SYNC_MID
        QUAD(0, 0)
        SYNC_END

        // ---------- P2: quad (0,1) ----------
#pragma unroll
        for (int ni = 2; ni < 4; ++ni) {
            bF[ni][0] = *(const short8*)&sm[dOff + bBase + ni * 1024 + sw0];
            bF[ni][1] = *(const short8*)&sm[dOff + bBase + ni * 1024 + sw1];
        }
        SYNC_MID
        QUAD(0, 1)
        SYNC_END

        // ---------- P3: quad (1,0); stage B(t+2) into buf d (B free after P2-end) ----------
#pragma unroll
        for (int mi = 0; mi < 4; ++mi) {
            aF[mi][0] = *(const short8*)&sm[dOff + aBase + (4 + mi) * 1024 + sw0];
            aF[mi][1] = *(const short8*)&sm[dOff + aBase + (4 + mi) * 1024 + sw1];
        }
        stageB(0, t2, d);
        stageB(1, t2, d);
        SYNC_MID
        QUAD(1, 0)
        SYNC_END

        // ---------- P4: quad (1,1); vmcnt(4) => tile t+1 resident; stage A(t+2) ----------
        __builtin_amdgcn_sched_barrier(0);
        asm volatile("s_waitcnt vmcnt(4)" ::: "memory");
        __builtin_amdgcn_sched_barrier(0);
        stageA(0, t2, d);              // A free after P3-end barrier
        stageA(1, t2, d);
        SYNC_MID
        QUAD(1, 1)
        SYNC_END
    }

    // drain dangling tail stages before epilogue/endpgm (LDS-DMA must not
    // outlive the workgroup)
    __builtin_amdgcn_sched_barrier(0);
    asm volatile("s_waitcnt vmcnt(0)" ::: "memory");
    __builtin_amdgcn_sched_barrier(0);

    // ---- epilogue: C/D layout col=lane&15, row=(lane>>4)*4+r
#pragma unroll
    for (int m = 0; m < 8; ++m) {
#pragma unroll
        for (int n = 0; n < 4; ++n) {
            int col = col0 + wc * 64 + n * 16 + lr;
            float bz = bias[col];
#pragma unroll
            for (int r = 0; r < 4; ++r) {
                int row = row0 + wr * 128 + m * 16 + lk4 * 4 + r;
                C[(size_t)row * NDIM + col] = acc[m][n][r] + bz;
            }
        }
    }
}

// ---------------- emergency fallback (ws too small / odd shape): exact fp32 ----------------
__global__ void fallback_kernel(const float* __restrict__ x, const int* __restrict__ wp,
                                const float* __restrict__ scales, const float* __restrict__ zeros,
                                const float* __restrict__ bias, float* __restrict__ out) {
    int o = blockIdx.x * 256 + threadIdx.x;
    int m = blockIdx.y;
    __shared__ float xs[KDIM];
    for (int i = threadIdx.x; i < KDIM; i += 256) xs[i] = x[(size_t)m * KDIM + i];
    __syncthreads();
    float acc = 0.f;
    for (int g = 0; g < 32; ++g) {
        float s = scales[o * 32 + g], z = zeros[o * 32 + g];
        float aq = 0.f, ax = 0.f;
        for (int j = 0; j < 32; ++j) {
            int p = wp[o * 1024 + g * 32 + j];
            int kb = g * 128 + j * 4;
#pragma unroll
            for (int q = 0; q < 4; ++q) {
                float xv = xs[kb + q];
                aq += xv * (float)((p >> (2 * q)) & 3);
                ax += xv;
            }
        }
        acc += s * aq + z * ax;
    }
    out[(size_t)m * NDIM + o] = acc + bias[o];
}

extern "C" void kernel_launch(void* const* d_in, const int* in_sizes, int n_in,
                              void* d_out, int out_size, void* d_ws, size_t ws_size,
                              hipStream_t stream) {
    const float* x      = (const float*)d_in[0];
    const int*   wp     = (const int*)d_in[1];
    const float* scales = (const float*)d_in[2];
    const float* zeros  = (const float*)d_in[3];
    const float* bias   = (const float*)d_in[4];
    float* out = (float*)d_out;

    const long M = (long)in_sizes[0] / KDIM;            // 8192
    const long PACKED = (long)in_sizes[1];              // 4194304
    const size_t need = (size_t)M * KDIM * 2 + (size_t)NDIM * KDIM * 2;  // 96 MB

    if (ws_size >= need && (M % 256) == 0) {
        unsigned short* xb = (unsigned short*)d_ws;
        unsigned short* wb = xb + (size_t)M * KDIM;
        cvt_x_kernel<<<(M * KDIM / 8) / 256, 256, 0, stream>>>(x, xb);
        dequant_w_kernel<<<(PACKED / 2) / 256, 256, 0, stream>>>(wp, scales, zeros, wb);
        int nwg = (int)(M / 256) * (NDIM / 256);        // 32*16 = 512, %8==0
        gemm256<<<nwg, 512, 0, stream>>>(xb, wb, bias, out);
    } else {
        dim3 grid(NDIM / 256, M);
        fallback_kernel<<<grid, 256, 0, stream>>>(x, wp, scales, zeros, bias, out);
    }
}